// Round 1
// baseline (394.415 us; speedup 1.0000x reference)
//
#include <hip/hip_runtime.h>
#include <hip/hip_bf16.h>
#include <stdint.h>

#define OUT_DIM 8192
#define IN_DIM  8192
#define GS      128
#define MROWS   32

typedef __attribute__((ext_vector_type(8))) short bf16x8;   // 8 bf16 = 4 VGPR (MFMA A/B frag)
typedef __attribute__((ext_vector_type(4))) float f32x4;    // MFMA C/D frag
typedef __attribute__((ext_vector_type(8))) unsigned short u16x8;

__device__ __forceinline__ unsigned short f2bf_rne(float f) {
    uint32_t v = __builtin_bit_cast(uint32_t, f);
    v += 0x7FFFu + ((v >> 16) & 1u);
    return (unsigned short)(v >> 16);
}

// Convert x (32x8192 fp32) -> bf16 in workspace. 262144 elems, 8/thread.
__global__ __launch_bounds__(256) void prep_xbf(const float* __restrict__ x,
                                                unsigned short* __restrict__ xbf) {
    int i = (blockIdx.x * 256 + threadIdx.x) * 8;
    float4 a = *(const float4*)(x + i);
    float4 b = *(const float4*)(x + i + 4);
    float f[8] = {a.x, a.y, a.z, a.w, b.x, b.y, b.z, b.w};
    u16x8 u;
#pragma unroll
    for (int j = 0; j < 8; ++j) u[j] = f2bf_rne(f[j]);
    *(u16x8*)(xbf + i) = u;
}

// out[t][o] = sum_k x[t][k] * ternary[o][k] * scale[o*64 + k/128]
// Wave tile: 16 output cols (o), 32 rows (t) via two 16x16x32 MFMAs, K-chunk 1024.
template <bool USE_WS>
__global__ __launch_bounds__(256, 4) void ternary_gemm(
    const int* __restrict__ tern, const float* __restrict__ scales,
    const float* __restrict__ xf, const unsigned short* __restrict__ xbf,
    float* __restrict__ out) {
    const int wave = blockIdx.x * 4 + (threadIdx.x >> 6);
    const int lane = threadIdx.x & 63;
    const int kc    = wave >> 9;     // 0..7   (split-K chunk)
    const int ntile = wave & 511;    // 0..511 (o-tile)
    const int n    = lane & 15;
    const int quad = lane >> 4;
    const int o      = (ntile << 4) + n;
    const int k0base = kc << 10;

    const int* __restrict__ wrow = tern + (size_t)o * IN_DIM;
    const int r0 = n, r1 = 16 + n;   // x rows for A frags (m = lane&15)

    f32x4 acc0 = {0.f, 0.f, 0.f, 0.f};
    f32x4 acc1 = {0.f, 0.f, 0.f, 0.f};

    for (int it = 0; it < 8; ++it) {
        const int k0 = k0base + (it << 7);            // 128-aligned -> single scale group
        const unsigned short sb = f2bf_rne(scales[o * (IN_DIM / GS) + (k0 >> 7)]);
        const unsigned int pos = sb, neg = sb | 0x8000u;
#pragma unroll
        for (int st = 0; st < 4; ++st) {
            const int k = k0 + (st << 5) + (quad << 3);   // this lane's 8 consecutive k
            // B fragment: 8 int32 ternary -> bf16x8 via sign-select (exact)
            int4 w0 = *(const int4*)(wrow + k);
            int4 w1 = *(const int4*)(wrow + k + 4);
            int tw[8] = {w0.x, w0.y, w0.z, w0.w, w1.x, w1.y, w1.z, w1.w};
            bf16x8 bfr;
#pragma unroll
            for (int j = 0; j < 8; ++j) {
                int t = tw[j];
                unsigned int u = (t < 0) ? neg : pos;
                bfr[j] = (short)((t == 0) ? 0u : u);
            }
            // A fragments: 8 consecutive bf16 of x rows r0, r1
            bf16x8 a0, a1;
            if constexpr (USE_WS) {
                a0 = *(const bf16x8*)(xbf + r0 * IN_DIM + k);
                a1 = *(const bf16x8*)(xbf + r1 * IN_DIM + k);
            } else {
                float4 xa = *(const float4*)(xf + r0 * IN_DIM + k);
                float4 xb = *(const float4*)(xf + r0 * IN_DIM + k + 4);
                float4 xc = *(const float4*)(xf + r1 * IN_DIM + k);
                float4 xd = *(const float4*)(xf + r1 * IN_DIM + k + 4);
                float fa[8] = {xa.x, xa.y, xa.z, xa.w, xb.x, xb.y, xb.z, xb.w};
                float fb[8] = {xc.x, xc.y, xc.z, xc.w, xd.x, xd.y, xd.z, xd.w};
#pragma unroll
                for (int j = 0; j < 8; ++j) { a0[j] = (short)f2bf_rne(fa[j]); a1[j] = (short)f2bf_rne(fb[j]); }
            }
            acc0 = __builtin_amdgcn_mfma_f32_16x16x32_bf16(a0, bfr, acc0, 0, 0, 0);
            acc1 = __builtin_amdgcn_mfma_f32_16x16x32_bf16(a1, bfr, acc1, 0, 0, 0);
        }
    }

    // Epilogue: D layout col = lane&15, row = quad*4 + reg. Split-K -> atomic add.
#pragma unroll
    for (int r = 0; r < 4; ++r) {
        const int t = quad * 4 + r;
        unsafeAtomicAdd(out + (size_t)t * OUT_DIM + o, acc0[r]);
        unsafeAtomicAdd(out + (size_t)(t + 16) * OUT_DIM + o, acc1[r]);
    }
}

extern "C" void kernel_launch(void* const* d_in, const int* in_sizes, int n_in,
                              void* d_out, int out_size, void* d_ws, size_t ws_size,
                              hipStream_t stream) {
    const float* x      = (const float*)d_in[0];
    const int*   tern   = (const int*)d_in[1];
    const float* scales = (const float*)d_in[2];
    float* out = (float*)d_out;
    unsigned short* xbf = (unsigned short*)d_ws;

    const bool use_ws = ws_size >= (size_t)MROWS * IN_DIM * sizeof(unsigned short);

    hipMemsetAsync(d_out, 0, (size_t)out_size * sizeof(float), stream);
    if (use_ws) {
        prep_xbf<<<(MROWS * IN_DIM) / (256 * 8), 256, 0, stream>>>(x, xbf);
        ternary_gemm<true><<<1024, 256, 0, stream>>>(tern, scales, x, xbf, out);
    } else {
        ternary_gemm<false><<<1024, 256, 0, stream>>>(tern, scales, x, xbf, out);
    }
}